// Round 16
// baseline (179.275 us; speedup 1.0000x reference)
//
#include <hip/hip_runtime.h>

typedef _Float16 h2 __attribute__((ext_vector_type(2)));
typedef _Float16 h8 __attribute__((ext_vector_type(8)));
typedef float f4 __attribute__((ext_vector_type(4)));

#define BB 256
#define II 1152
#define QQ 8
#define JJ 10
#define PP 16

#define BT 32            // b per block: 2 per thread (256 thr = 16 bg x 16 p)
#define IT 4             // i per block (small tile -> grid 2304, 9216 waves)
#define NBT (BB / BT)    // 8
#define NIT (II / IT)    // 288
#define XRH 40           // halfs per staged-x b-row (32 + 8 pad)
#define WTILE (IT * PP * QQ)     // 512 halfs per j in the LDS W-tile

#define NW (JJ * II * PP * QQ)   // 1474560
#define NX (BB * II * QQ)        // 2359296
#define NS (BB * JJ * PP)        // 40960
#define LOG2E 1.4426950408889634f

// ---------------------------------------------------------------------------
// 16-lane row sum via DPP (VALU pipe only).
// ---------------------------------------------------------------------------
template <int CTRL>
__device__ __forceinline__ float dpp_add(float v) {
    int s = __builtin_bit_cast(int, v);
    int t = __builtin_amdgcn_update_dpp(0, s, CTRL, 0xF, 0xF, true);
    return v + __builtin_bit_cast(float, t);
}
__device__ __forceinline__ float row_sum16(float v) {
    v = dpp_add<0xB1>(v);   // xor1
    v = dpp_add<0x4E>(v);   // xor2
    v = dpp_add<0x124>(v);  // row_ror:4
    v = dpp_add<0x128>(v);  // row_ror:8
    return v;
}

// 8-element f16 dot with fp32 accumulate: 4 x v_dot2_f32_f16.
__device__ __forceinline__ float dot8(h8 w, h8 x) {
    h2 w0 = __builtin_shufflevector(w, w, 0, 1), w1 = __builtin_shufflevector(w, w, 2, 3);
    h2 w2 = __builtin_shufflevector(w, w, 4, 5), w3 = __builtin_shufflevector(w, w, 6, 7);
    h2 x0 = __builtin_shufflevector(x, x, 0, 1), x1 = __builtin_shufflevector(x, x, 2, 3);
    h2 x2 = __builtin_shufflevector(x, x, 4, 5), x3 = __builtin_shufflevector(x, x, 6, 7);
    float acc = __builtin_amdgcn_fdot2(w0, x0, 0.0f, false);
    acc = __builtin_amdgcn_fdot2(w1, x1, acc, false);
    acc = __builtin_amdgcn_fdot2(w2, x2, acc, false);
    acc = __builtin_amdgcn_fdot2(w3, x3, acc, false);
    return acc;
}

// ---------------------------------------------------------------------------
// prep: W,X fp32 -> f16; zero S0/S1/S2 (contiguous).
// ---------------------------------------------------------------------------
__global__ __launch_bounds__(256) void prep_kernel(
    const float* __restrict__ X, const float* __restrict__ W,
    _Float16* __restrict__ Xh, _Float16* __restrict__ Wh,
    float* __restrict__ S)   // 3*NS floats
{
    const int g = blockIdx.x * 256 + threadIdx.x;
    const int stride = gridDim.x * 256;
    typedef _Float16 h4 __attribute__((ext_vector_type(4)));
    for (int k = g; k < NW / 4; k += stride) {
        const float4 f = ((const float4*)W)[k];
        h4 o = { (_Float16)f.x, (_Float16)f.y, (_Float16)f.z, (_Float16)f.w };
        ((h4*)Wh)[k] = o;
    }
    for (int k = g; k < NX / 4; k += stride) {
        const float4 f = ((const float4*)X)[k];
        h4 o = { (_Float16)f.x, (_Float16)f.y, (_Float16)f.z, (_Float16)f.w };
        ((h4*)Xh)[k] = o;
    }
    const float4 z = {0.f, 0.f, 0.f, 0.f};
    for (int k = g; k < 3 * NS / 4; k += stride) ((float4*)S)[k] = z;
}

// ---------------------------------------------------------------------------
// s0 via MFMA (verified in R13): s0 = 0.1 * GEMM over K=(i,q)=9216.
// ---------------------------------------------------------------------------
__global__ __launch_bounds__(256) void s0_mfma_kernel(
    const _Float16* __restrict__ Xh, const _Float16* __restrict__ Wh,
    float* __restrict__ S0)
{
    const int wid  = blockIdx.x * 4 + (threadIdx.x >> 6);  // 0..1279
    const int lane = threadIdx.x & 63;
    const int bt  = wid / 80;
    const int rem = wid % 80;
    const int j   = rem >> 3;
    const int kc  = rem & 7;
    const int b0  = bt * 16;
    const int m    = lane & 15;
    const int quad = lane >> 4;
    const int ib   = kc * 144;

    const _Float16* ax = Xh + ((size_t)(b0 + m) * II + ib + quad) * QQ;
    const _Float16* bw = Wh + (((size_t)j * II + ib + quad) * PP + m) * QQ;

    f4 acc = {0.f, 0.f, 0.f, 0.f};
    for (int t = 0; t < 36; ++t) {
        const h8 a = *(const h8*)ax;
        const h8 b = *(const h8*)bw;
        acc = __builtin_amdgcn_mfma_f32_16x16x32_f16(a, b, acc, 0, 0, 0);
        ax += 4 * QQ;
        bw += (size_t)4 * PP * QQ;
    }
#pragma unroll
    for (int r = 0; r < 4; ++r)
        atomicAdd(&S0[((size_t)(b0 + quad * 4 + r) * JJ + j) * PP + m], 0.1f * acc[r]);
}

// ---------------------------------------------------------------------------
// Fused routing pass (R=1,2), LDS-fed, 2 b per thread, IT=4.
// Thread = (b_l 0..15, p); batches bA=b0+b_l, bB=bA+16.
// vs R13: same wave count (2304 blk x 256 thr = 9216 waves -> TLP preserved,
// the R15 mistake), but each W ds_read_b128 feeds 2 b (LDS pipe halved:
// 40 reads/thread vs 80) and W staging traffic halves (NBT 16->8).
// Cost: atomics per S-slot 144->288 (R11 showed atomics aren't the floor).
// R15 proved this body compiles spill-free at VGPR 56.
// ---------------------------------------------------------------------------
template <int R>
__global__ __launch_bounds__(256, 4) void pass_kernel(
    const _Float16* __restrict__ Xh,  // [B][I][Q] f16
    const _Float16* __restrict__ Wh,  // [J][I][P][Q] f16
    const float* __restrict__ Sprev,  // [B][J][P]
    float* __restrict__ V0,           // v0 raw (R1 writes it==0, R2 reads)
    float* __restrict__ Sout)         // [B][J][P] pre-zeroed accumulator
{
    __shared__ _Float16 ws[JJ * WTILE];  // 10.25 KB
    __shared__ _Float16 xs[BT * XRH];    // 2.5 KB

    const int bt = blockIdx.x & (NBT - 1);
    const int it = blockIdx.x >> 3;
    const int b0 = bt * BT;
    const int i0 = it * IT;
    const int tid = threadIdx.x;

    // ---- stage W tile: 640 h8 chunks (10j x 64) over 256 threads
    {
        const size_t jstride = (size_t)II * PP * QQ;
        const _Float16* wsrc = Wh + (size_t)i0 * PP * QQ;
        for (int c = tid; c < JJ * (WTILE / 8); c += 256) {
            const int j = c >> 6;          // 64 h8 chunks per j
            const int r = c & 63;
            *(h8*)(ws + j * WTILE + r * 8) = *(const h8*)(wsrc + j * jstride + r * 8);
        }
        // ---- stage x tile: 32 b x 4 h8 = 128 chunks (first 128 threads)
        if (tid < 128) {
            const int xb = tid >> 2;
            const int xr = tid & 3;
            *(h8*)(xs + xb * XRH + xr * 8) =
                *(const h8*)(Xh + ((size_t)(b0 + xb) * II + i0) * QQ + xr * 8);
        }
    }
    __syncthreads();

    const int b_l = tid >> 4;           // 0..15
    const int p   = tid & 15;
    const int bA  = b0 + b_l;
    const int bB  = bA + 16;

    // inline squash of Sprev -> vv for both batches (pre-scaled by log2e)
    float vvA[JJ], vvB[JJ];
#pragma unroll
    for (int j = 0; j < JJ; ++j) {
        const float spA = Sprev[((size_t)bA * JJ + j) * PP + p];
        const float spB = Sprev[((size_t)bB * JJ + j) * PP + p];
        const float nA = row_sum16(spA * spA);
        const float nB = row_sum16(spB * spB);
        const float scA = nA * __builtin_amdgcn_rcpf(1.0f + nA)
                             * __builtin_amdgcn_rsqf(nA + 1e-7f);
        const float scB = nB * __builtin_amdgcn_rcpf(1.0f + nB)
                             * __builtin_amdgcn_rsqf(nB + 1e-7f);
        float vA = spA * scA;
        float vB = spB * scB;
        if (R == 1) {
            if (it == 0) {
                V0[((size_t)bA * JJ + j) * PP + p] = vA;
                V0[((size_t)bB * JJ + j) * PP + p] = vB;
            }
        } else {
            vA += V0[((size_t)bA * JJ + j) * PP + p];
            vB += V0[((size_t)bB * JJ + j) * PP + p];
        }
        vvA[j] = vA * LOG2E;
        vvB[j] = vB * LOG2E;
    }

    float saccA[JJ], saccB[JJ];
#pragma unroll
    for (int j = 0; j < JJ; ++j) { saccA[j] = 0.0f; saccB[j] = 0.0f; }

    const _Float16* wb = ws + p * QQ;    // single LDS base; imm offsets below
    const _Float16* xa = xs + b_l * XRH;
    const _Float16* xbp = xs + (b_l + 16) * XRH;

#pragma unroll
    for (int i = 0; i < IT; ++i) {
        const h8 x8A = *(const h8*)(xa + i * QQ);
        const h8 x8B = *(const h8*)(xbp + i * QQ);

        float hA[JJ], hB[JJ];
#pragma unroll
        for (int j = 0; j < JJ; ++j) {
            const h8 w8 = *(const h8*)(wb + j * WTILE + i * PP * QQ);  // shared read
            hA[j] = dot8(w8, x8A);
            hB[j] = dot8(w8, x8B);
        }

        float eA[JJ], eB[JJ];
#pragma unroll
        for (int j = 0; j < JJ; ++j) {
            const float bjA = row_sum16(vvA[j] * hA[j]);   // 2 indep DPP chains
            const float bjB = row_sum16(vvB[j] * hB[j]);
            eA[j] = __builtin_amdgcn_exp2f(bjA);
            eB[j] = __builtin_amdgcn_exp2f(bjB);
        }
        float aA0 = (eA[0] + eA[1]) + (eA[2] + eA[3]);
        float aA1 = (eA[4] + eA[5]) + (eA[6] + eA[7]);
        const float sumA = (aA0 + aA1) + (eA[8] + eA[9]);
        float aB0 = (eB[0] + eB[1]) + (eB[2] + eB[3]);
        float aB1 = (eB[4] + eB[5]) + (eB[6] + eB[7]);
        const float sumB = (aB0 + aB1) + (eB[8] + eB[9]);
        const float invA = __builtin_amdgcn_rcpf(sumA);
        const float invB = __builtin_amdgcn_rcpf(sumB);
#pragma unroll
        for (int j = 0; j < JJ; ++j) {
            saccA[j] += (eA[j] * invA) * hA[j];
            saccB[j] += (eB[j] * invB) * hB[j];
        }
    }

#pragma unroll
    for (int j = 0; j < JJ; ++j) {
        atomicAdd(&Sout[((size_t)bA * JJ + j) * PP + p], saccA[j]);
        atomicAdd(&Sout[((size_t)bB * JJ + j) * PP + p], saccB[j]);
    }
}

// ---------------------------------------------------------------------------
// final output squash (fp32 precise)
// ---------------------------------------------------------------------------
__global__ __launch_bounds__(256) void squash_out_kernel(const float* __restrict__ S,
                                                         float* __restrict__ V)
{
    const int idx = blockIdx.x * blockDim.x + threadIdx.x;  // (b*J + j)
    if (idx >= BB * JJ) return;
    const float4* sp = (const float4*)(S + idx * PP);
    float4 a = sp[0], b4 = sp[1], c4 = sp[2], d4 = sp[3];
    float s2 = a.x * a.x + a.y * a.y + a.z * a.z + a.w * a.w +
               b4.x * b4.x + b4.y * b4.y + b4.z * b4.z + b4.w * b4.w +
               c4.x * c4.x + c4.y * c4.y + c4.z * c4.z + c4.w * c4.w +
               d4.x * d4.x + d4.y * d4.y + d4.z * d4.z + d4.w * d4.w;
    const float scale = s2 / (1.0f + s2) / sqrtf(s2 + 1e-7f);
    a.x *= scale; a.y *= scale; a.z *= scale; a.w *= scale;
    b4.x *= scale; b4.y *= scale; b4.z *= scale; b4.w *= scale;
    c4.x *= scale; c4.y *= scale; c4.z *= scale; c4.w *= scale;
    d4.x *= scale; d4.y *= scale; d4.z *= scale; d4.w *= scale;
    float4* vp = (float4*)(V + idx * PP);
    vp[0] = a; vp[1] = b4; vp[2] = c4; vp[3] = d4;
}

extern "C" void kernel_launch(void* const* d_in, const int* in_sizes, int n_in,
                              void* d_out, int out_size, void* d_ws, size_t ws_size,
                              hipStream_t stream)
{
    const float* X = (const float*)d_in[0];  // [256][1152][8]
    const float* W = (const float*)d_in[1];  // [10][1152][16][8]
    float* out = (float*)d_out;              // [256][10][16]

    _Float16* Xh = (_Float16*)d_ws;          // NX halfs
    _Float16* Wh = Xh + NX;                  // NW halfs
    float* S0 = (float*)(Wh + NW);           // NS floats
    float* S1 = S0 + NS;
    float* S2 = S1 + NS;
    float* v0 = S2 + NS;                     // NS floats; total ~8.3 MB

    const int grid = NBT * NIT;              // 2304 blocks of 256 threads

    prep_kernel<<<1024, 256, 0, stream>>>(X, W, Xh, Wh, S0);
    s0_mfma_kernel<<<320, 256, 0, stream>>>(Xh, Wh, S0);
    pass_kernel<1><<<grid, 256, 0, stream>>>(Xh, Wh, S0, v0, S1);
    pass_kernel<2><<<grid, 256, 0, stream>>>(Xh, Wh, S1, v0, S2);
    squash_out_kernel<<<10, 256, 0, stream>>>(S2, out);
}

// Round 18
// 133.339 us; speedup vs baseline: 1.3445x; 1.3445x over previous
//
#include <hip/hip_runtime.h>

typedef _Float16 h2 __attribute__((ext_vector_type(2)));
typedef _Float16 h8 __attribute__((ext_vector_type(8)));
typedef float f4 __attribute__((ext_vector_type(4)));

#define BB 256
#define II 1152
#define QQ 8
#define JJ 10
#define PP 16

#define BT 16            // b per block (R13 config — best measured)
#define IT 8             // i per block
#define NBT (BB / BT)    // 16
#define NIT (II / IT)    // 144
#define XRH 72           // halfs per staged-x b-row (64 + 8 pad)
#define WTILE (IT * PP * QQ)     // 1024 halfs per j in the LDS W-tile

#define NW (JJ * II * PP * QQ)   // 1474560
#define NX (BB * II * QQ)        // 2359296
#define NS (BB * JJ * PP)        // 40960
#define LOG2E 1.4426950408889634f

// ---------------------------------------------------------------------------
// 16-lane row sum via DPP — f32 (for vv_kernel) and packed-f16 (hot loop).
// ---------------------------------------------------------------------------
template <int CTRL>
__device__ __forceinline__ float dpp_add(float v) {
    int s = __builtin_bit_cast(int, v);
    int t = __builtin_amdgcn_update_dpp(0, s, CTRL, 0xF, 0xF, true);
    return v + __builtin_bit_cast(float, t);
}
__device__ __forceinline__ float row_sum16(float v) {
    v = dpp_add<0xB1>(v);   // xor1
    v = dpp_add<0x4E>(v);   // xor2
    v = dpp_add<0x124>(v);  // row_ror:4
    v = dpp_add<0x128>(v);  // row_ror:8
    return v;
}
template <int CTRL>
__device__ __forceinline__ h2 dpp_add_pk(h2 v) {
    int s = __builtin_bit_cast(int, v);
    int t = __builtin_amdgcn_update_dpp(0, s, CTRL, 0xF, 0xF, true);
    return v + __builtin_bit_cast(h2, t);   // v_pk_add_f16
}
__device__ __forceinline__ h2 row_sum16_pk(h2 v) {
    v = dpp_add_pk<0xB1>(v);
    v = dpp_add_pk<0x4E>(v);
    v = dpp_add_pk<0x124>(v);
    v = dpp_add_pk<0x128>(v);
    return v;
}

// 8-element f16 dot with fp32 accumulate: 4 x v_dot2_f32_f16.
__device__ __forceinline__ float dot8(h8 w, h8 x) {
    h2 w0 = __builtin_shufflevector(w, w, 0, 1), w1 = __builtin_shufflevector(w, w, 2, 3);
    h2 w2 = __builtin_shufflevector(w, w, 4, 5), w3 = __builtin_shufflevector(w, w, 6, 7);
    h2 x0 = __builtin_shufflevector(x, x, 0, 1), x1 = __builtin_shufflevector(x, x, 2, 3);
    h2 x2 = __builtin_shufflevector(x, x, 4, 5), x3 = __builtin_shufflevector(x, x, 6, 7);
    float acc = __builtin_amdgcn_fdot2(w0, x0, 0.0f, false);
    acc = __builtin_amdgcn_fdot2(w1, x1, acc, false);
    acc = __builtin_amdgcn_fdot2(w2, x2, acc, false);
    acc = __builtin_amdgcn_fdot2(w3, x3, acc, false);
    return acc;
}

// ---------------------------------------------------------------------------
// prep: W,X fp32 -> f16; zero S0/S1/S2 (contiguous).
// ---------------------------------------------------------------------------
__global__ __launch_bounds__(256) void prep_kernel(
    const float* __restrict__ X, const float* __restrict__ W,
    _Float16* __restrict__ Xh, _Float16* __restrict__ Wh,
    float* __restrict__ S)   // 3*NS floats
{
    const int g = blockIdx.x * 256 + threadIdx.x;
    const int stride = gridDim.x * 256;
    typedef _Float16 h4 __attribute__((ext_vector_type(4)));
    for (int k = g; k < NW / 4; k += stride) {
        const float4 f = ((const float4*)W)[k];
        h4 o = { (_Float16)f.x, (_Float16)f.y, (_Float16)f.z, (_Float16)f.w };
        ((h4*)Wh)[k] = o;
    }
    for (int k = g; k < NX / 4; k += stride) {
        const float4 f = ((const float4*)X)[k];
        h4 o = { (_Float16)f.x, (_Float16)f.y, (_Float16)f.z, (_Float16)f.w };
        ((h4*)Xh)[k] = o;
    }
    const float4 z = {0.f, 0.f, 0.f, 0.f};
    for (int k = g; k < 3 * NS / 4; k += stride) ((float4*)S)[k] = z;
}

// ---------------------------------------------------------------------------
// s0 via MFMA (verified in R13): s0 = 0.1 * GEMM over K=(i,q)=9216.
// ---------------------------------------------------------------------------
__global__ __launch_bounds__(256) void s0_mfma_kernel(
    const _Float16* __restrict__ Xh, const _Float16* __restrict__ Wh,
    float* __restrict__ S0)
{
    const int wid  = blockIdx.x * 4 + (threadIdx.x >> 6);  // 0..1279
    const int lane = threadIdx.x & 63;
    const int bt  = wid / 80;
    const int rem = wid % 80;
    const int j   = rem >> 3;
    const int kc  = rem & 7;
    const int b0  = bt * 16;
    const int m    = lane & 15;
    const int quad = lane >> 4;
    const int ib   = kc * 144;

    const _Float16* ax = Xh + ((size_t)(b0 + m) * II + ib + quad) * QQ;
    const _Float16* bw = Wh + (((size_t)j * II + ib + quad) * PP + m) * QQ;

    f4 acc = {0.f, 0.f, 0.f, 0.f};
    for (int t = 0; t < 36; ++t) {
        const h8 a = *(const h8*)ax;
        const h8 b = *(const h8*)bw;
        acc = __builtin_amdgcn_mfma_f32_16x16x32_f16(a, b, acc, 0, 0, 0);
        ax += 4 * QQ;
        bw += (size_t)4 * PP * QQ;
    }
#pragma unroll
    for (int r = 0; r < 4; ++r)
        atomicAdd(&S0[((size_t)(b0 + quad * 4 + r) * JJ + j) * PP + m], 0.1f * acc[r]);
}

// ---------------------------------------------------------------------------
// vv_kernel: squash + logit-weight precompute (hoisted out of pass prologue).
//  MODE 0: v = squash(S);  V0raw = v;  VV = v * log2e      (after s0)
//  MODE 1: v = squash(S);  VV = (v + V0raw) * log2e        (after pass 1)
// idx = (b*J + j)*16 + p; lanes 0-15 = one (b,j) row -> DPP row_sum16.
// ---------------------------------------------------------------------------
template <int MODE>
__global__ __launch_bounds__(256) void vv_kernel(
    const float* __restrict__ S, float* __restrict__ V0raw,
    float* __restrict__ VV)
{
    const int idx = blockIdx.x * 256 + threadIdx.x;   // 0..NS-1
    const float s = S[idx];
    const float n2 = row_sum16(s * s);
    const float sc = n2 * __builtin_amdgcn_rcpf(1.0f + n2)
                        * __builtin_amdgcn_rsqf(n2 + 1e-7f);
    const float v = s * sc;
    if (MODE == 0) {
        V0raw[idx] = v;
        VV[idx] = v * LOG2E;
    } else {
        VV[idx] = (v + V0raw[idx]) * LOG2E;
    }
}

// ---------------------------------------------------------------------------
// Fused routing pass, LDS-fed (R13 structure), R-agnostic: VV precomputed.
// Thread = (b_l, p). Hot loop per i:
//   h[j] = dot8(ws, x8)                       (10 ds_read_b128, shared)
//   logit j-pairs: cvt_pkrtz -> 4x(DPP+pk_add) packed-f16 16-lane reduction
//   softmax (native exp2), sacc += c*h
// ---------------------------------------------------------------------------
__global__ __launch_bounds__(256, 4) void pass_kernel(
    const _Float16* __restrict__ Xh,  // [B][I][Q] f16
    const _Float16* __restrict__ Wh,  // [J][I][P][Q] f16
    const float* __restrict__ VV,     // [B][J][P] = v * log2e
    float* __restrict__ Sout)         // [B][J][P] pre-zeroed accumulator
{
    __shared__ _Float16 ws[JJ * WTILE];  // 20 KB
    __shared__ _Float16 xs[BT * XRH];    // 2.25 KB

    const int bt = blockIdx.x & (NBT - 1);
    const int it = blockIdx.x >> 4;
    const int b0 = bt * BT;
    const int i0 = it * IT;
    const int tid = threadIdx.x;

    // ---- stage W tile: 1280 h8 chunks, 5 per thread (coalesced 16B/lane)
    {
        const size_t jstride = (size_t)II * PP * QQ;
        const _Float16* wsrc = Wh + (size_t)i0 * PP * QQ;
#pragma unroll
        for (int k = 0; k < 5; ++k) {
            const int c = tid + k * 256;   // 0..1279
            const int j = c >> 7;          // 128 h8 chunks per j
            const int r = c & 127;
            *(h8*)(ws + j * WTILE + r * 8) = *(const h8*)(wsrc + j * jstride + r * 8);
        }
        if (tid < 128) {
            const int xb = tid >> 3;
            const int xr = tid & 7;
            *(h8*)(xs + xb * XRH + xr * 8) =
                *(const h8*)(Xh + ((size_t)(b0 + xb) * II + i0) * QQ + xr * 8);
        }
    }
    __syncthreads();

    const int b_l = tid >> 4;
    const int p   = tid & 15;
    const int b   = b0 + b_l;

    // precomputed vv (10 loads; 16-lane coalesced per (b,j) segment)
    float vv[JJ];
#pragma unroll
    for (int j = 0; j < JJ; ++j)
        vv[j] = VV[((size_t)b * JJ + j) * PP + p];

    float sacc[JJ];
#pragma unroll
    for (int j = 0; j < JJ; ++j) sacc[j] = 0.0f;

    const _Float16* wb = ws + p * QQ;    // single LDS base; imm offsets below
    const _Float16* xb = xs + b_l * XRH;

#pragma unroll
    for (int i = 0; i < IT; ++i) {
        const h8 x8 = *(const h8*)(xb + i * QQ);

        float h[JJ];
#pragma unroll
        for (int j = 0; j < JJ; ++j)
            h[j] = dot8(*(const h8*)(wb + j * WTILE + i * PP * QQ), x8);

        // packed-f16 16-lane logit reduction, j-pairs (5 packs, 40 insts)
        float e[JJ];
#pragma unroll
        for (int jp = 0; jp < JJ; jp += 2) {
            const h2 pk = __builtin_bit_cast(h2,
                __builtin_amdgcn_cvt_pkrtz(vv[jp] * h[jp],
                                           vv[jp + 1] * h[jp + 1]));
            const h2 r = row_sum16_pk(pk);
            e[jp]     = __builtin_amdgcn_exp2f((float)r.x);
            e[jp + 1] = __builtin_amdgcn_exp2f((float)r.y);
        }
        float a0 = (e[0] + e[1]) + (e[2] + e[3]);
        float a1 = (e[4] + e[5]) + (e[6] + e[7]);
        const float sum = (a0 + a1) + (e[8] + e[9]);
        const float inv = __builtin_amdgcn_rcpf(sum);
#pragma unroll
        for (int j = 0; j < JJ; ++j) sacc[j] += (e[j] * inv) * h[j];
    }

#pragma unroll
    for (int j = 0; j < JJ; ++j)
        atomicAdd(&Sout[((size_t)b * JJ + j) * PP + p], sacc[j]);
}

// ---------------------------------------------------------------------------
// final output squash (fp32 precise)
// ---------------------------------------------------------------------------
__global__ __launch_bounds__(256) void squash_out_kernel(const float* __restrict__ S,
                                                         float* __restrict__ V)
{
    const int idx = blockIdx.x * blockDim.x + threadIdx.x;  // (b*J + j)
    if (idx >= BB * JJ) return;
    const float4* sp = (const float4*)(S + idx * PP);
    float4 a = sp[0], b4 = sp[1], c4 = sp[2], d4 = sp[3];
    float s2 = a.x * a.x + a.y * a.y + a.z * a.z + a.w * a.w +
               b4.x * b4.x + b4.y * b4.y + b4.z * b4.z + b4.w * b4.w +
               c4.x * c4.x + c4.y * c4.y + c4.z * c4.z + c4.w * c4.w +
               d4.x * d4.x + d4.y * d4.y + d4.z * d4.z + d4.w * d4.w;
    const float scale = s2 / (1.0f + s2) / sqrtf(s2 + 1e-7f);
    a.x *= scale; a.y *= scale; a.z *= scale; a.w *= scale;
    b4.x *= scale; b4.y *= scale; b4.z *= scale; b4.w *= scale;
    c4.x *= scale; c4.y *= scale; c4.z *= scale; c4.w *= scale;
    d4.x *= scale; d4.y *= scale; d4.z *= scale; d4.w *= scale;
    float4* vp = (float4*)(V + idx * PP);
    vp[0] = a; vp[1] = b4; vp[2] = c4; vp[3] = d4;
}

extern "C" void kernel_launch(void* const* d_in, const int* in_sizes, int n_in,
                              void* d_out, int out_size, void* d_ws, size_t ws_size,
                              hipStream_t stream)
{
    const float* X = (const float*)d_in[0];  // [256][1152][8]
    const float* W = (const float*)d_in[1];  // [10][1152][16][8]
    float* out = (float*)d_out;              // [256][10][16]

    _Float16* Xh = (_Float16*)d_ws;          // NX halfs
    _Float16* Wh = Xh + NX;                  // NW halfs
    float* S0 = (float*)(Wh + NW);           // NS floats
    float* S1 = S0 + NS;
    float* S2 = S1 + NS;
    float* V0raw = S2 + NS;                  // NS floats
    float* VV1   = V0raw + NS;               // NS floats
    float* VV2   = VV1 + NS;                 // NS floats; total ~8.6 MB

    const int grid  = NBT * NIT;             // 2304 blocks of 256 threads
    const int vgrid = NS / 256;              // 160 blocks

    prep_kernel<<<1024, 256, 0, stream>>>(X, W, Xh, Wh, S0);
    s0_mfma_kernel<<<320, 256, 0, stream>>>(Xh, Wh, S0);
    vv_kernel<0><<<vgrid, 256, 0, stream>>>(S0, V0raw, VV1);
    pass_kernel<<<grid, 256, 0, stream>>>(Xh, Wh, VV1, S1);
    vv_kernel<1><<<vgrid, 256, 0, stream>>>(S1, V0raw, VV2);
    pass_kernel<<<grid, 256, 0, stream>>>(Xh, Wh, VV2, S2);
    squash_out_kernel<<<10, 256, 0, stream>>>(S2, out);
}